// Round 5
// baseline (295.344 us; speedup 1.0000x reference)
//
#include <hip/hip_runtime.h>

// Match the jax/XLA-CPU reference's fp32 semantics exactly:
//  - f32 denormals FLUSHED in & out (XLA CPU runs FTZ+DAZ; Round-4 evidence:
//    flush moved loss from 3.3e-39 to 3.66e-33 vs ref 8.14e-33)
//  - FMA contraction in the LLVM-canonical positions (XLA attaches contract
//    flags; fadd(fmul,z)->fma, fsub(fmul,fmul)->fma(a,b,-(c*d)))
//  - everything else separately rounded in reference order (contract off here
//    so OUR compiler adds/removes nothing)
#pragma clang fp contract(off)

#define B_    32
#define NDEL_ 16
#define K_    10
#define T_    16384
#define N0_   2048   // round(T/8)

// DPP row_shr:1 : lane i receives lane i-1's value within its 16-lane row;
// row-leading lane gets 0 (bound_ctrl). Exact stage->stage bit hand-off.
__device__ __forceinline__ float dpp_shr1(float v) {
    int i = __builtin_bit_cast(int, v);
    int r = __builtin_amdgcn_update_dpp(0, i, 0x111 /*row_shr:1*/, 0xF, 0xF, true);
    return __builtin_bit_cast(float, r);
}

__global__ __launch_bounds__(256, 1)
void sos_gamma_kernel(const float* __restrict__ sos, float* __restrict__ out) {
#pragma clang fp contract(off)
    // MODE.FP_DENORM (bits [7:4]) = 0xC : f32 flush-in/flush-out (DAZ+FTZ,
    // sign-preserving — XLA CPU semantics), f64/f16 IEEE.
    // hwreg(MODE=1, offset=4, size=4) -> 1 | (4<<6) | ((4-1)<<11) = 6401
    __builtin_amdgcn_s_setreg(6401, 0xC);

    const int tid  = threadIdx.x;
    const int wave = tid >> 6;
    const int lane = tid & 63;
    const int row  = lane >> 4;      // 4 lines per wave64 (one per 16-lane DPP row)
    const int st   = lane & 15;      // cascade stage within row (0..9 active)
    const int d    = (wave << 2) | row;          // NDEL index 0..15
    const int line = blockIdx.x * NDEL_ + d;     // line = b*16 + d, b = blockIdx.x

    // Coefficients; a0 == 1.0 exactly so the division is exact. Idle lanes: 0.
    float b0 = 0.f, b1 = 0.f, b2 = 0.f, a1 = 0.f, a2 = 0.f;
    if (st < K_) {
        const float* c = sos + (size_t)line * (K_ * 6) + st * 6;
        const float a0 = c[3];
        b0 = c[0] / a0;
        b1 = c[1] / a0;
        b2 = c[2] / a0;
        a1 = c[4] / a0;
        a2 = c[5] / a0;
    }

    float z1 = 0.f, z2 = 0.f;
    float y  = 0.f;
    float hacc = 0.f, tacc = 0.f;

    // XLA-contracted step:
    //   y   = fma(b0, x, z1)
    //   z1' = fma(b1, x, -(a1*y)) + z2     (a1*y separately rounded)
    //   z2' = fma(b2, x, -(a2*y))          (a2*y separately rounded)
#define STEP(XEXPR)                                \
    do {                                           \
        float x  = (XEXPR);                        \
        y        = __builtin_fmaf(b0, x, z1);      \
        float t3 = a1 * y;                         \
        float t4 = __builtin_fmaf(b1, x, -t3);     \
        float t6 = a2 * y;                         \
        z1       = t4 + z2;                        \
        z2       = __builtin_fmaf(b2, x, -t6);     \
    } while (0)

    // tick 0: unit impulse enters stage 0.
    STEP((st == 0) ? 1.0f : 0.0f);

    // Pipeline skew: stage k processes sample t at tick t+k; lane 9 emits y(t)
    // at tick t+9.  ticks 1..8: fill.
#pragma unroll
    for (int tau = 1; tau <= 8; ++tau) { STEP(dpp_shr1(y)); }

    // ticks 9..2056: head window, t in [0, 2048)
#pragma unroll 4
    for (int tau = 9; tau <= 8 + N0_; ++tau) {
        STEP(dpp_shr1(y));
        hacc += fabsf(y);
    }

    // ticks 2057..14344: middle, t in [2048, 14336)
#pragma unroll 8
    for (int tau = 9 + N0_; tau <= 8 + (T_ - N0_); ++tau) { STEP(dpp_shr1(y)); }

    // ticks 14345..16392: tail window, t in [14336, 16384)
#pragma unroll 4
    for (int tau = 9 + (T_ - N0_); tau <= 8 + T_; ++tau) {
        STEP(dpp_shr1(y));
        tacc += fabsf(y);
    }
#undef STEP

    // Per-line gamma from the last stage's lane; block == one b-group (16 lines).
    __shared__ float gam[NDEL_];
    if (st == 9) gam[d] = tacc / hacc;
    __syncthreads();

    if (tid == 0) {
        float num = 0.f, den = 0.f;
        for (int i = 0; i < NDEL_; ++i) {
            float g = gam[i];
            float w = expf(g);   // gamma ~ 1e-33 -> w == 1.0f
            num += g * w;
            den += w;
        }
        atomicAdd(out, num / den);
    }
}

extern "C" void kernel_launch(void* const* d_in, const int* in_sizes, int n_in,
                              void* d_out, int out_size, void* d_ws, size_t ws_size,
                              hipStream_t stream) {
    (void)in_sizes; (void)n_in; (void)d_ws; (void)ws_size; (void)out_size;
    const float* sos = (const float*)d_in[0];
    float* out = (float*)d_out;

    // d_out is re-poisoned 0xAA before every timed launch — zero it (capturable).
    hipMemsetAsync(out, 0, sizeof(float), stream);

    // 32 blocks (one per B index) x 256 threads (4 waves x 4 lines = 16 lines).
    sos_gamma_kernel<<<B_, 256, 0, stream>>>(sos, out);
}

// Round 6
// 291.309 us; speedup vs baseline: 1.0139x; 1.0139x over previous
//
#include <hip/hip_runtime.h>

// Bit-exact match of the jax/XLA-CPU reference (verified Round 5, absmax 0.0):
//  - f32 FTZ+DAZ (MODE.FP_DENORM=0xC)
//  - XLA/LLVM-canonical FMA contraction, all else separately rounded
// This round: skew-2 systolic schedule — the DPP lane hand-off gets a full
// tick of slack so v_mov_dpp latency/hazard pipelines off the critical chain.
// Arithmetic sequence per stage is IDENTICAL to the passing kernel.
#pragma clang fp contract(off)

#define B_    32
#define NDEL_ 16
#define K_    10
#define T_    16384
#define N0_   2048   // round(T/8)

__device__ __forceinline__ float dpp_shr1(float v) {
    int i = __builtin_bit_cast(int, v);
    int r = __builtin_amdgcn_update_dpp(0, i, 0x111 /*row_shr:1*/, 0xF, 0xF, true);
    return __builtin_bit_cast(float, r);
}

__global__ __launch_bounds__(256, 1)
void sos_gamma_kernel(const float* __restrict__ sos, float* __restrict__ out) {
#pragma clang fp contract(off)
    // f32 flush-in/flush-out, f16/f64 IEEE (XLA CPU semantics).
    __builtin_amdgcn_s_setreg(6401, 0xC);

    const int tid  = threadIdx.x;
    const int wave = tid >> 6;
    const int lane = tid & 63;
    const int row  = lane >> 4;      // 4 lines per wave64 (one per 16-lane DPP row)
    const int st   = lane & 15;      // cascade stage within row (0..9 active)
    const int d    = (wave << 2) | row;          // NDEL index 0..15
    const int line = blockIdx.x * NDEL_ + d;

    float b0 = 0.f, b1 = 0.f, b2 = 0.f, a1 = 0.f, a2 = 0.f;
    if (st < K_) {
        const float* c = sos + (size_t)line * (K_ * 6) + st * 6;
        const float a0 = c[3];
        b0 = c[0] / a0;
        b1 = c[1] / a0;
        b2 = c[2] / a0;
        a1 = c[4] / a0;
        a2 = c[5] / a0;
    }

    float z1 = 0.f, z2 = 0.f;
    float hacc = 0.f, tacc = 0.f;

    // Ping-pong y registers and x hand-off buffers.
    // Schedule (skew 2): stage k handles sample t at tick tau = t + 2k.
    //   even tick: x = xb1; xb2 = dpp(yA); compute yB
    //   odd  tick: x = xb2; xb1 = dpp(yB); compute yA
    // Each dpp is issued a full tick before its consumption.
    float yA = 0.f, yB = 0.f;
    float xb1 = (st == 0) ? 1.0f : 0.0f;   // x(0) = impulse into stage 0
    float xb2 = 0.f;

    // XLA-contracted biquad step (bit-exact, verified):
#define STEPX(XV, YOUT)                                \
    do {                                               \
        float x_ = (XV);                               \
        YOUT     = __builtin_fmaf(b0, x_, z1);         \
        float t3 = a1 * YOUT;                          \
        float t4 = __builtin_fmaf(b1, x_, -t3);        \
        float t6 = a2 * YOUT;                          \
        z1       = t4 + z2;                            \
        z2       = __builtin_fmaf(b2, x_, -t6);        \
    } while (0)

#define NOACC(YV)  do { } while (0)
#define HACC(YV)   do { hacc += fabsf(YV); } while (0)
#define TACC(YV)   do { tacc += fabsf(YV); } while (0)

#define TICK2(ACCUM)                                        \
    do {                                                    \
        float xA = xb1; xb2 = dpp_shr1(yA);                 \
        STEPX(xA, yB); ACCUM(yB);                           \
        float xB = xb2; xb1 = dpp_shr1(yB);                 \
        STEPX(xB, yA); ACCUM(yA);                           \
    } while (0)

    // Lane 9 emits y(t) at tick t+18. Total ticks: 16402 (8201 pairs).
    // fill: ticks 0..17  (9 pairs)
#pragma unroll
    for (int p = 0; p < 9; ++p)    { TICK2(NOACC); }
    // head: ticks 18..2065  -> t in [0, 2048)   (1024 pairs)
#pragma unroll 4
    for (int p = 0; p < 1024; ++p) { TICK2(HACC); }
    // middle: ticks 2066..14353 -> t in [2048, 14336)  (6144 pairs)
#pragma unroll 4
    for (int p = 0; p < 6144; ++p) { TICK2(NOACC); }
    // tail: ticks 14354..16401 -> t in [14336, 16384)  (1024 pairs)
#pragma unroll 4
    for (int p = 0; p < 1024; ++p) { TICK2(TACC); }

#undef TICK2
#undef STEPX
#undef NOACC
#undef HACC
#undef TACC

    // Per-line gamma from the last stage's lane; block == one b-group (16 lines).
    __shared__ float gam[NDEL_];
    if (st == 9) gam[d] = tacc / hacc;
    __syncthreads();

    if (tid == 0) {
        float num = 0.f, den = 0.f;
        for (int i = 0; i < NDEL_; ++i) {
            float g = gam[i];
            float w = expf(g);   // gamma ~ 1e-33 -> w == 1.0f
            num += g * w;
            den += w;
        }
        atomicAdd(out, num / den);
    }
}

extern "C" void kernel_launch(void* const* d_in, const int* in_sizes, int n_in,
                              void* d_out, int out_size, void* d_ws, size_t ws_size,
                              hipStream_t stream) {
    (void)in_sizes; (void)n_in; (void)d_ws; (void)ws_size; (void)out_size;
    const float* sos = (const float*)d_in[0];
    float* out = (float*)d_out;

    // d_out is re-poisoned 0xAA before every timed launch — zero it (capturable).
    hipMemsetAsync(out, 0, sizeof(float), stream);

    // 32 blocks (one per B index) x 256 threads (4 waves x 4 lines = 16 lines).
    sos_gamma_kernel<<<B_, 256, 0, stream>>>(sos, out);
}